// Round 6
// baseline (535.988 us; speedup 1.0000x reference)
//
#include <hip/hip_runtime.h>

// RelativePositionEncoding: O[i,j,c] = Wt[dres][c] + Wt[66+dtok][c]
//                                    + same_entity*Wt[132][c] + Wt[133+dchain][c]
// Wt[b][c] = W[c*139 + b]. Store-BW bound (537 MB fp32 out, floor ~85 us).
// R5->R6: amortize non-storing phases. Each block owns 4 consecutive i rows:
// W staged once per 4 rows (512 stagings vs 2048); j-bins for row i+1 are
// computed into a double-buffered jb_pack WHILE row i's store loop runs
// (one barrier per row). 512 blocks = exactly 2/CU, tail-free.

#define R_MAX 32
#define NO_BINS 139
#define C_Z 128
#define C_HALF 64
#define N_MAX 1024     // harness N = 1024
#define WSTRIDE 68     // padded LDS row stride (words)
#define IPB 4          // i rows per block

typedef float v4f __attribute__((ext_vector_type(4)));

__global__ __launch_bounds__(256) void relpos_kernel(
    const int* __restrict__ asym, const int* __restrict__ res,
    const int* __restrict__ ent,  const int* __restrict__ tok,
    const int* __restrict__ sym,  const float* __restrict__ W,
    float* __restrict__ out, int N)
{
    __shared__ float wt[NO_BINS * WSTRIDE];  // 37,808 B: wt[b*68+c]
    __shared__ int   jb_pack[2][N_MAX];      //  8,192 B, double-buffered

    const int tid   = threadIdx.x;
    const int c_off = blockIdx.x * C_HALF;
    const int i0    = blockIdx.y * IPB;

    // --- stage W half: coalesced float4 reads of the contiguous c-half,
    //     transposed padded LDS writes (8-way write conflict, cheap) ---
    const float* __restrict__ Wr = W + (size_t)c_off * NO_BINS;  // 8896 floats
    for (int q = tid; q < (C_HALF * NO_BINS) / 4; q += 256) {    // 2224 float4
        const v4f v = *(const v4f*)(Wr + 4 * q);
        const int e = 4 * q;
#pragma unroll
        for (int k = 0; k < 4; ++k) {
            const int ee = e + k;
            const int c  = ee / NO_BINS;        // magic-mul div
            const int b  = ee - c * NO_BINS;
            wt[b * WSTRIDE + c] = v[k];
        }
    }

    // --- bins for first row into buffer 0 ---
    {
        const int i = i0;
        const int ai = asym[i], ri = res[i], ei = ent[i], ti = tok[i], si = sym[i];
        for (int j = tid; j < N; j += 256) {
            const int rj = res[j], tj = tok[j], aj = asym[j], ej = ent[j], sj = sym[j];
            const bool sc  = (ai == aj);
            const bool sr  = (ri == rj);
            const bool seB = (ei == ej);
            int dr = min(max(ri - rj + R_MAX, 0), 2 * R_MAX);
            if (!sc) dr = 2 * R_MAX + 1;
            int dt = min(max(ti - tj + R_MAX, 0), 2 * R_MAX);
            if (!(sc && sr)) dt = 2 * R_MAX + 1;
            int dc = min(max(si - sj + 2, 0), 4);
            if (!seB) dc = 5;
            jb_pack[0][j] = dr | ((66 + dt) << 7) | ((133 + dc) << 15)
                               | ((seB ? 1 : 0) << 23);
        }
    }
    __syncthreads();

    const int c4 = (tid & 15) * 4;  // lane's 4-float slice within the c-half
    const int jl = tid >> 4;        // 0..15: j within chunk
    const v4f entv = *(const v4f*)&wt[132 * WSTRIDE + c4];

    for (int k = 0; k < IPB; ++k) {
        const int i = i0 + k;

        // --- prefetch bins for next row into the other buffer (overlaps
        //     with this row's store loop; latency hidden) ---
        if (k + 1 < IPB) {
            const int ii = i + 1;
            const int ai = asym[ii], ri = res[ii], ei = ent[ii],
                      ti = tok[ii], si = sym[ii];
            for (int j = tid; j < N; j += 256) {
                const int rj = res[j], tj = tok[j], aj = asym[j],
                          ej = ent[j], sj = sym[j];
                const bool sc  = (ai == aj);
                const bool sr  = (ri == rj);
                const bool seB = (ei == ej);
                int dr = min(max(ri - rj + R_MAX, 0), 2 * R_MAX);
                if (!sc) dr = 2 * R_MAX + 1;
                int dt = min(max(ti - tj + R_MAX, 0), 2 * R_MAX);
                if (!(sc && sr)) dt = 2 * R_MAX + 1;
                int dc = min(max(si - sj + 2, 0), 4);
                if (!seB) dc = 5;
                jb_pack[(k + 1) & 1][j] = dr | ((66 + dt) << 7) | ((133 + dc) << 15)
                                             | ((seB ? 1 : 0) << 23);
            }
        }

        // --- store loop for row i: LDS-only reads, nontemporal stores ---
        const int* __restrict__ bp = jb_pack[k & 1];
        float* po = out + ((size_t)i * N + jl) * C_Z + c_off + c4;

        for (int jb = 0; jb < N; jb += 16) {
            const int pk   = bp[jb + jl];       // broadcast within 16-lane group
            const int rowR = pk & 127;
            const int rowT = (pk >> 7) & 255;
            const int rowC = (pk >> 15) & 255;
            const float se = (pk >> 23) ? 1.0f : 0.0f;

            const v4f r0 = *(const v4f*)&wt[rowR * WSTRIDE + c4];
            const v4f t0 = *(const v4f*)&wt[rowT * WSTRIDE + c4];
            const v4f k0 = *(const v4f*)&wt[rowC * WSTRIDE + c4];

            v4f o;
            o.x = fmaf(se, entv.x, r0.x + t0.x + k0.x);
            o.y = fmaf(se, entv.y, r0.y + t0.y + k0.y);
            o.z = fmaf(se, entv.z, r0.z + t0.z + k0.z);
            o.w = fmaf(se, entv.w, r0.w + t0.w + k0.w);

            __builtin_nontemporal_store(o, (v4f*)po);
            po += 16 * C_Z;
        }
        __syncthreads();   // bins[k+1] ready; readers of bp done before reuse
    }
}

extern "C" void kernel_launch(void* const* d_in, const int* in_sizes, int n_in,
                              void* d_out, int out_size, void* d_ws, size_t ws_size,
                              hipStream_t stream) {
    const int*   asym = (const int*)d_in[0];
    const int*   res  = (const int*)d_in[1];
    const int*   ent  = (const int*)d_in[2];
    const int*   tok  = (const int*)d_in[3];
    const int*   sym  = (const int*)d_in[4];
    const float* W    = (const float*)d_in[5];
    float* out = (float*)d_out;

    const int N = in_sizes[0];  // B = 1, N = 1024 (divisible by IPB)
    dim3 grid(C_Z / C_HALF, N / IPB);
    relpos_kernel<<<grid, 256, 0, stream>>>(asym, res, ent, tok, sym, W, out, N);
}

// Round 7
// 535.207 us; speedup vs baseline: 1.0015x; 1.0015x over previous
//
#include <hip/hip_runtime.h>

// RelativePositionEncoding: O[i,j,c] = Wt[dres][c] + Wt[66+dtok][c]
//                                    + same_entity*Wt[132][c] + Wt[133+dchain][c]
// Wt[b][c] = W[c*139 + b]. Store-BW bound (537 MB fp32 out, floor ~85 us).
// R6->R7: single-variable experiment off the best kernel (R5): drop the
// nontemporal store flag (isolating it; it was bundled into R5). The fill
// kernel reaches 6.3 TB/s with normal stores through L2 write-back; nt may
// route through a slower no-allocate path. Everything else identical to R5.

#define R_MAX 32
#define NO_BINS 139
#define C_Z 128
#define C_HALF 64
#define N_MAX 1024     // harness N = 1024
#define WSTRIDE 68     // padded LDS row stride (words)

typedef float v4f __attribute__((ext_vector_type(4)));

__global__ __launch_bounds__(256) void relpos_kernel(
    const int* __restrict__ asym, const int* __restrict__ res,
    const int* __restrict__ ent,  const int* __restrict__ tok,
    const int* __restrict__ sym,  const float* __restrict__ W,
    float* __restrict__ out, int N)
{
    __shared__ float wt[NO_BINS * WSTRIDE];  // 37,808 B: wt[b*68+c]
    __shared__ int   jb_pack[N_MAX];         //  4,096 B

    const int tid   = threadIdx.x;
    const int c_off = blockIdx.x * C_HALF;
    const int i     = blockIdx.y;

    // --- stage W half: coalesced float4 reads of the contiguous c-half,
    //     transposed padded LDS writes (8-way write conflict, cheap) ---
    const float* __restrict__ Wr = W + (size_t)c_off * NO_BINS;  // 8896 floats
    for (int q = tid; q < (C_HALF * NO_BINS) / 4; q += 256) {    // 2224 float4
        const v4f v = *(const v4f*)(Wr + 4 * q);
        const int e = 4 * q;
#pragma unroll
        for (int k = 0; k < 4; ++k) {
            const int ee = e + k;
            const int c  = ee / NO_BINS;        // magic-mul div
            const int b  = ee - c * NO_BINS;
            wt[b * WSTRIDE + c] = v[k];
        }
    }

    // --- i-side scalars (block-uniform) ---
    const int ai = asym[i], ri = res[i], ei = ent[i], ti = tok[i], si = sym[i];

    // --- per-j packed bins, computed once per block (coalesced loads) ---
    for (int j = tid; j < N; j += 256) {
        const int rj = res[j], tj = tok[j], aj = asym[j], ej = ent[j], sj = sym[j];
        const bool sc  = (ai == aj);
        const bool sr  = (ri == rj);
        const bool seB = (ei == ej);

        int dr = min(max(ri - rj + R_MAX, 0), 2 * R_MAX);
        if (!sc) dr = 2 * R_MAX + 1;                    // 65
        int dt = min(max(ti - tj + R_MAX, 0), 2 * R_MAX);
        if (!(sc && sr)) dt = 2 * R_MAX + 1;            // 65
        int dc = min(max(si - sj + 2, 0), 4);
        if (!seB) dc = 5;

        jb_pack[j] = dr | ((66 + dt) << 7) | ((133 + dc) << 15) | ((seB ? 1 : 0) << 23);
    }
    __syncthreads();

    // --- main loop: LDS-only reads, one coalesced 16B/lane store ---
    const int c4 = (tid & 15) * 4;  // lane's 4-float slice within the c-half
    const int jl = tid >> 4;        // 0..15: j within chunk

    const v4f entv = *(const v4f*)&wt[132 * WSTRIDE + c4];

    float* po = out + ((size_t)i * N + jl) * C_Z + c_off + c4;

    for (int jb = 0; jb < N; jb += 16) {
        const int pk   = jb_pack[jb + jl];      // broadcast within 16-lane group
        const int rowR = pk & 127;
        const int rowT = (pk >> 7) & 255;
        const int rowC = (pk >> 15) & 255;
        const float se = (pk >> 23) ? 1.0f : 0.0f;

        const v4f r0 = *(const v4f*)&wt[rowR * WSTRIDE + c4];
        const v4f t0 = *(const v4f*)&wt[rowT * WSTRIDE + c4];
        const v4f k0 = *(const v4f*)&wt[rowC * WSTRIDE + c4];

        v4f o;
        o.x = fmaf(se, entv.x, r0.x + t0.x + k0.x);
        o.y = fmaf(se, entv.y, r0.y + t0.y + k0.y);
        o.z = fmaf(se, entv.z, r0.z + t0.z + k0.z);
        o.w = fmaf(se, entv.w, r0.w + t0.w + k0.w);

        // 16B/lane; 16 lanes/j -> 256B contiguous per j; NORMAL store (no nt)
        *(v4f*)po = o;
        po += 16 * C_Z;
    }
}

extern "C" void kernel_launch(void* const* d_in, const int* in_sizes, int n_in,
                              void* d_out, int out_size, void* d_ws, size_t ws_size,
                              hipStream_t stream) {
    const int*   asym = (const int*)d_in[0];
    const int*   res  = (const int*)d_in[1];
    const int*   ent  = (const int*)d_in[2];
    const int*   tok  = (const int*)d_in[3];
    const int*   sym  = (const int*)d_in[4];
    const float* W    = (const float*)d_in[5];
    float* out = (float*)d_out;

    const int N = in_sizes[0];  // B = 1, N = 1024
    dim3 grid(C_Z / C_HALF, N);
    relpos_kernel<<<grid, 256, 0, stream>>>(asym, res, ent, tok, sym, W, out, N);
}